// Round 4
// baseline (1167.219 us; speedup 1.0000x reference)
//
#include <hip/hip_runtime.h>

// KGAT 3-layer forward. Inputs (all f32/int32, setup_inputs order):
// 0 embed[N,64], 1 w1_0[64,64], 2 b1_0, 3 w2_0, 4 b2_0,
// 5 w1_1[32,64], 6 b1_1, 7 w2_1, 8 b2_1, 9 w1_2[16,32], 10 b1_2, 11 w2_2, 12 b2_2,
// 13 edge_val[E], 14 edge_row[E], 15 edge_col[E]
// Output f32 [N,176] = [embed | l2n(ego1) | l2n(ego2) | l2n(ego3)]

#define NODES 100000
#define OUT_STRIDE 176

typedef _Float16 half2_t __attribute__((ext_vector_type(2)));
typedef _Float16 half4_t __attribute__((ext_vector_type(4)));
typedef _Float16 half8_t __attribute__((ext_vector_type(8)));

static constexpr int SCAN_TILE = 1024;
static constexpr int NV = NODES + 1;
static constexpr int NBLK = (NV + SCAN_TILE - 1) / SCAN_TILE;  // 98
static constexpr int DBUCK = 64;

// ---------------- CSR build ----------------

__global__ void hist_kernel(const int* __restrict__ rows, int* __restrict__ counts,
                            int* __restrict__ rank, int e) {
    int i = blockIdx.x * blockDim.x + threadIdx.x;
    if (i < e) rank[i] = atomicAdd(&counts[rows[i]], 1);
}

__global__ __launch_bounds__(1024) void scan_reduce_kernel(const int* __restrict__ counts,
                                                           int* __restrict__ blockSums) {
    int i = blockIdx.x * SCAN_TILE + threadIdx.x;
    int v = (i < NODES) ? counts[i] : 0;
    #pragma unroll
    for (int off = 32; off; off >>= 1) v += __shfl_xor(v, off);
    __shared__ int ws[16];
    int lane = threadIdx.x & 63, wid = threadIdx.x >> 6;
    if (lane == 0) ws[wid] = v;
    __syncthreads();
    if (threadIdx.x == 0) {
        int t = 0;
        for (int k = 0; k < 16; ++k) t += ws[k];
        blockSums[blockIdx.x] = t;
    }
}

__global__ void scan_offsets_kernel(const int* __restrict__ blockSums, int* __restrict__ blockOffs) {
    __shared__ int s[NBLK];
    if (threadIdx.x < NBLK) s[threadIdx.x] = blockSums[threadIdx.x];
    __syncthreads();
    if (threadIdx.x == 0) {
        int run = 0;
        for (int b = 0; b < NBLK; ++b) { int t = s[b]; s[b] = run; run += t; }
    }
    __syncthreads();
    if (threadIdx.x < NBLK) blockOffs[threadIdx.x] = s[threadIdx.x];
}

__global__ __launch_bounds__(1024) void scan_write_kernel(const int* __restrict__ counts,
                                                          const int* __restrict__ blockOffs,
                                                          int* __restrict__ row_ptr) {
    int i = blockIdx.x * SCAN_TILE + threadIdx.x;
    int lane = threadIdx.x & 63, wid = threadIdx.x >> 6;
    int v = (i < NODES) ? counts[i] : 0;
    int incl = v;
    #pragma unroll
    for (int off = 1; off < 64; off <<= 1) {
        int t = __shfl_up(incl, off);
        if (lane >= off) incl += t;
    }
    __shared__ int wsum[16];
    if (lane == 63) wsum[wid] = incl;
    __syncthreads();
    if (wid == 0) {
        int wv = (lane < 16) ? wsum[lane] : 0;
        int wincl = wv;
        #pragma unroll
        for (int off = 1; off < 16; off <<= 1) {
            int t = __shfl_up(wincl, off);
            if (lane >= off) wincl += t;
        }
        if (lane < 16) wsum[lane] = wincl - wv;  // exclusive wave offsets
    }
    __syncthreads();
    int excl = incl - v + wsum[wid] + blockOffs[blockIdx.x];
    if (i < NV) row_ptr[i] = excl;
}

// pack edge: col (17 bits) | round(val*32767) << 17
__global__ void fill_kernel(const int* __restrict__ rows, const int* __restrict__ cols,
                            const float* __restrict__ vals, const int* __restrict__ row_ptr,
                            const int* __restrict__ rank, unsigned* __restrict__ se, int e) {
    int i = blockIdx.x * blockDim.x + threadIdx.x;
    if (i < e) {
        unsigned v15 = __float2uint_rn(vals[i] * 32767.f);
        se[row_ptr[rows[i]] + rank[i]] = (unsigned)cols[i] | (v15 << 17);
    }
}

// ---------------- degree-sorted row permutation (load balance) ----------------

__global__ __launch_bounds__(1024) void deg_hist_kernel(const int* __restrict__ counts,
                                                        int* __restrict__ dhist) {
    __shared__ int lh[DBUCK];
    if (threadIdx.x < DBUCK) lh[threadIdx.x] = 0;
    __syncthreads();
    int i = blockIdx.x * 1024 + threadIdx.x;
    if (i < NODES) atomicAdd(&lh[min(counts[i], DBUCK - 1)], 1);
    __syncthreads();
    if (threadIdx.x < DBUCK && lh[threadIdx.x]) atomicAdd(&dhist[threadIdx.x], lh[threadIdx.x]);
}

__global__ void deg_scan_kernel(const int* __restrict__ dhist, int* __restrict__ dcur) {
    if (threadIdx.x == 0) {
        int run = 0;
        for (int d = DBUCK - 1; d >= 0; --d) { dcur[d] = run; run += dhist[d]; }  // descending degree
    }
}

__global__ __launch_bounds__(1024) void perm_kernel(const int* __restrict__ counts,
                                                    int* __restrict__ dcur,
                                                    int* __restrict__ perm) {
    __shared__ int lh[DBUCK], lbase[DBUCK];
    if (threadIdx.x < DBUCK) lh[threadIdx.x] = 0;
    __syncthreads();
    int i = blockIdx.x * 1024 + threadIdx.x;
    int d = 0, lrank = 0;
    if (i < NODES) {
        d = min(counts[i], DBUCK - 1);
        lrank = atomicAdd(&lh[d], 1);
    }
    __syncthreads();
    if (threadIdx.x < DBUCK && lh[threadIdx.x])
        lbase[threadIdx.x] = atomicAdd(&dcur[threadIdx.x], lh[threadIdx.x]);
    __syncthreads();
    if (i < NODES) perm[lbase[d] + lrank] = i;
}

// ------- cols 0..63 = raw embed (f32) + build fp16 copy of embed -------

__global__ void prep_embed_kernel(const float4* __restrict__ x4, float4* __restrict__ out4,
                                  half4_t* __restrict__ xh) {
    int i = blockIdx.x * blockDim.x + threadIdx.x;
    if (i < NODES * 16) {
        int r = i >> 4, c = i & 15;
        float4 v = x4[i];
        out4[r * (OUT_STRIDE / 4) + c] = v;
        xh[i] = half4_t{(_Float16)v.x, (_Float16)v.y, (_Float16)v.z, (_Float16)v.w};
    }
}

// ---------------- fused layer: spmm + aggregate + l2norm ----------------
// Rows processed in degree-sorted order via perm[] (divergence-free waves).
// x fp16 [n,DIN]; LPR=DIN/4 lanes/row, RPW rows/wave. Edge loop unrolled x8
// (8 gathers in flight/group). Aggregation: lane owns outputs o=li+LPR*k;
// weights [o][d2] in LDS with 144B rows -> ds_read_b128 conflict-free.

template <int DIN, int DOUT>
__global__ __launch_bounds__(256, 6) void layer_kernel(
    const half4_t* __restrict__ xh, const unsigned* __restrict__ edges,
    const int* __restrict__ row_ptr, const int* __restrict__ perm,
    const float* __restrict__ w1, const float* __restrict__ b1,
    const float* __restrict__ w2, const float* __restrict__ b2,
    _Float16* __restrict__ ego_out,  // [n, DOUT] fp16 (null for last layer)
    float* __restrict__ outp,        // d_out + column offset, row stride 176
    int n) {
    constexpr int LPR = DIN / 4;        // lanes per row
    constexpr int RPW = 64 / LPR;       // rows per wave
    constexpr int RPB = 4 * RPW;        // rows per block
    constexpr int OPL = DOUT / LPR;     // outputs per lane
    constexpr int SW = DIN / 2 + 4;     // half2 per weight row (144B/80B, 16B-aligned)
    constexpr int SROWH = DIN + 8;      // halves per sum row (144B/80B)
    constexpr int NB = DIN / 8;         // half8 blocks per row

    __shared__ half2_t w1T[DOUT * SW], w2T[DOUT * SW];   // [o][d2]
    __shared__ _Float16 sum_h[4][RPW][SROWH], bi_h[4][RPW][SROWH];

    for (int idx = threadIdx.x; idx < DOUT * (DIN / 2); idx += 256) {
        int o = idx / (DIN / 2), d2 = idx % (DIN / 2);
        w1T[o * SW + d2] = half2_t{(_Float16)w1[o * DIN + 2 * d2], (_Float16)w1[o * DIN + 2 * d2 + 1]};
        w2T[o * SW + d2] = half2_t{(_Float16)w2[o * DIN + 2 * d2], (_Float16)w2[o * DIN + 2 * d2 + 1]};
    }
    __syncthreads();

    int wid = threadIdx.x >> 6, lane = threadIdx.x & 63;
    int g = lane / LPR;     // row-group within wave
    int li = lane % LPR;    // half4 chunk within row

    float bb1[OPL], bb2[OPL];
    #pragma unroll
    for (int k = 0; k < OPL; ++k) { bb1[k] = b1[li + LPR * k]; bb2[k] = b2[li + LPR * k]; }

    for (int base = blockIdx.x * RPB; base < n; base += gridDim.x * RPB) {
        int idx = base + wid * RPW + g;
        bool valid = idx < n;
        int r = valid ? perm[idx] : 0;
        int s = valid ? row_ptr[r] : 0;
        int eend = valid ? row_ptr[r + 1] : 0;

        half4_t egoh = xh[(size_t)r * LPR + li];  // issue early
        float sx = 0.f, sy = 0.f, sz = 0.f, sw_ = 0.f;

        int j = s;
        while (j < eend) {
            unsigned pk[8];
            half4_t xv[8];
            #pragma unroll
            for (int k = 0; k < 8; ++k) {
                int jj = j + k;
                unsigned p = edges[jj < eend ? jj : s];
                pk[k] = (jj < eend) ? p : 0u;
            }
            #pragma unroll
            for (int k = 0; k < 8; ++k)
                xv[k] = xh[(size_t)(pk[k] & 0x1FFFFu) * LPR + li];
            #pragma unroll
            for (int k = 0; k < 8; ++k) {
                float vf = (float)(pk[k] >> 17);
                sx += vf * (float)xv[k].x;
                sy += vf * (float)xv[k].y;
                sz += vf * (float)xv[k].z;
                sw_ += vf * (float)xv[k].w;
            }
            j += 8;
        }
        constexpr float SCL = 1.f / 32767.f;
        float4 side = make_float4(sx * SCL, sy * SCL, sz * SCL, sw_ * SCL);

        float ex = (float)egoh.x, ey = (float)egoh.y, ez = (float)egoh.z, ew = (float)egoh.w;
        half4_t sm4 = half4_t{(_Float16)(ex + side.x), (_Float16)(ey + side.y),
                              (_Float16)(ez + side.z), (_Float16)(ew + side.w)};
        half4_t bi4 = half4_t{(_Float16)(ex * side.x), (_Float16)(ey * side.y),
                              (_Float16)(ez * side.z), (_Float16)(ew * side.w)};
        *(half4_t*)&sum_h[wid][g][li * 4] = sm4;   // wave-private, no barrier
        *(half4_t*)&bi_h[wid][g][li * 4] = bi4;

        float a1[OPL], a2[OPL];
        #pragma unroll
        for (int k = 0; k < OPL; ++k) { a1[k] = bb1[k]; a2[k] = bb2[k]; }

        const half8_t* svp = (const half8_t*)&sum_h[wid][g][0];
        const half8_t* tvp = (const half8_t*)&bi_h[wid][g][0];
        #pragma unroll
        for (int d2b = 0; d2b < NB; ++d2b) {
            half8_t sv = svp[d2b], tv = tvp[d2b];
            half2_t s01 = __builtin_shufflevector(sv, sv, 0, 1);
            half2_t s23 = __builtin_shufflevector(sv, sv, 2, 3);
            half2_t s45 = __builtin_shufflevector(sv, sv, 4, 5);
            half2_t s67 = __builtin_shufflevector(sv, sv, 6, 7);
            half2_t t01 = __builtin_shufflevector(tv, tv, 0, 1);
            half2_t t23 = __builtin_shufflevector(tv, tv, 2, 3);
            half2_t t45 = __builtin_shufflevector(tv, tv, 4, 5);
            half2_t t67 = __builtin_shufflevector(tv, tv, 6, 7);
            #pragma unroll
            for (int k = 0; k < OPL; ++k) {
                int o = li + LPR * k;
                half8_t wa = *(const half8_t*)&w1T[o * SW + d2b * 4];
                half8_t wb = *(const half8_t*)&w2T[o * SW + d2b * 4];
                half2_t wa01 = __builtin_shufflevector(wa, wa, 0, 1);
                half2_t wa23 = __builtin_shufflevector(wa, wa, 2, 3);
                half2_t wa45 = __builtin_shufflevector(wa, wa, 4, 5);
                half2_t wa67 = __builtin_shufflevector(wa, wa, 6, 7);
                half2_t wb01 = __builtin_shufflevector(wb, wb, 0, 1);
                half2_t wb23 = __builtin_shufflevector(wb, wb, 2, 3);
                half2_t wb45 = __builtin_shufflevector(wb, wb, 4, 5);
                half2_t wb67 = __builtin_shufflevector(wb, wb, 6, 7);
#if __has_builtin(__builtin_amdgcn_fdot2)
                a1[k] = __builtin_amdgcn_fdot2(s01, wa01, a1[k], false);
                a1[k] = __builtin_amdgcn_fdot2(s23, wa23, a1[k], false);
                a1[k] = __builtin_amdgcn_fdot2(s45, wa45, a1[k], false);
                a1[k] = __builtin_amdgcn_fdot2(s67, wa67, a1[k], false);
                a2[k] = __builtin_amdgcn_fdot2(t01, wb01, a2[k], false);
                a2[k] = __builtin_amdgcn_fdot2(t23, wb23, a2[k], false);
                a2[k] = __builtin_amdgcn_fdot2(t45, wb45, a2[k], false);
                a2[k] = __builtin_amdgcn_fdot2(t67, wb67, a2[k], false);
#else
                a1[k] = fmaf((float)s01.x, (float)wa01.x, fmaf((float)s01.y, (float)wa01.y, a1[k]));
                a1[k] = fmaf((float)s23.x, (float)wa23.x, fmaf((float)s23.y, (float)wa23.y, a1[k]));
                a1[k] = fmaf((float)s45.x, (float)wa45.x, fmaf((float)s45.y, (float)wa45.y, a1[k]));
                a1[k] = fmaf((float)s67.x, (float)wa67.x, fmaf((float)s67.y, (float)wa67.y, a1[k]));
                a2[k] = fmaf((float)t01.x, (float)wb01.x, fmaf((float)t01.y, (float)wb01.y, a2[k]));
                a2[k] = fmaf((float)t23.x, (float)wb23.x, fmaf((float)t23.y, (float)wb23.y, a2[k]));
                a2[k] = fmaf((float)t45.x, (float)wb45.x, fmaf((float)t45.y, (float)wb45.y, a2[k]));
                a2[k] = fmaf((float)t67.x, (float)wb67.x, fmaf((float)t67.y, (float)wb67.y, a2[k]));
#endif
            }
        }

        float ov[OPL];
        float sq = 0.f;
        #pragma unroll
        for (int k = 0; k < OPL; ++k) {
            float u1 = a1[k] > 0.f ? a1[k] : 0.01f * a1[k];
            float u2 = a2[k] > 0.f ? a2[k] : 0.01f * a2[k];
            ov[k] = u1 + u2;
            sq += ov[k] * ov[k];
        }
        #pragma unroll
        for (int off = 1; off < LPR; off <<= 1) sq += __shfl_xor(sq, off);
        float inv = 1.f / fmaxf(sqrtf(sq), 1e-12f);

        if (valid) {
            #pragma unroll
            for (int k = 0; k < OPL; ++k) {
                int o = li + LPR * k;
                if (ego_out) ego_out[(size_t)r * DOUT + o] = (_Float16)ov[k];
                outp[(size_t)r * OUT_STRIDE + o] = ov[k] * inv;
            }
        }
    }
}

// ---------------- launch ----------------

static size_t align_up(size_t x) { return (x + 255) & ~(size_t)255; }

extern "C" void kernel_launch(void* const* d_in, const int* in_sizes, int n_in,
                              void* d_out, int out_size, void* d_ws, size_t ws_size,
                              hipStream_t stream) {
    const float* embed = (const float*)d_in[0];
    const float* w1_0 = (const float*)d_in[1];  const float* b1_0 = (const float*)d_in[2];
    const float* w2_0 = (const float*)d_in[3];  const float* b2_0 = (const float*)d_in[4];
    const float* w1_1 = (const float*)d_in[5];  const float* b1_1 = (const float*)d_in[6];
    const float* w2_1 = (const float*)d_in[7];  const float* b2_1 = (const float*)d_in[8];
    const float* w1_2 = (const float*)d_in[9];  const float* b1_2 = (const float*)d_in[10];
    const float* w2_2 = (const float*)d_in[11]; const float* b2_2 = (const float*)d_in[12];
    const float* edge_val = (const float*)d_in[13];
    const int*   edge_row = (const int*)d_in[14];
    const int*   edge_col = (const int*)d_in[15];
    const int E = in_sizes[14];
    const int N = in_sizes[0] / 64;
    float* out = (float*)d_out;

    // workspace carve-up (~43 MB)
    char* ws = (char*)d_ws;
    size_t off = 0;
    int* counts    = (int*)(ws + off); off = align_up(off + (size_t)N * 4);
    int* row_ptr   = (int*)(ws + off); off = align_up(off + (size_t)(N + 1) * 4);
    int* rank      = (int*)(ws + off); off = align_up(off + (size_t)E * 4);
    int* blockSums = (int*)(ws + off); off = align_up(off + (size_t)NBLK * 4);
    int* blockOffs = (int*)(ws + off); off = align_up(off + (size_t)NBLK * 4);
    int* dhist     = (int*)(ws + off); off = align_up(off + (size_t)DBUCK * 4);
    int* dcur      = (int*)(ws + off); off = align_up(off + (size_t)DBUCK * 4);
    int* perm      = (int*)(ws + off); off = align_up(off + (size_t)N * 4);
    unsigned* sorted = (unsigned*)(ws + off); off = align_up(off + (size_t)E * 4);
    half4_t* embed_h = (half4_t*)(ws + off); off = align_up(off + (size_t)N * 64 * 2);
    _Float16* ego1_h = (_Float16*)(ws + off); off = align_up(off + (size_t)N * 64 * 2);
    _Float16* ego2_h = (_Float16*)(ws + off); off = align_up(off + (size_t)N * 32 * 2);
    (void)ws_size; (void)n_in; (void)out_size;

    hipMemsetAsync(counts, 0, (size_t)N * 4, stream);
    hipMemsetAsync(dhist, 0, (size_t)DBUCK * 4, stream);

    int eg = (E + 255) / 256;
    hist_kernel<<<eg, 256, 0, stream>>>(edge_row, counts, rank, E);
    scan_reduce_kernel<<<NBLK, 1024, 0, stream>>>(counts, blockSums);
    scan_offsets_kernel<<<1, 128, 0, stream>>>(blockSums, blockOffs);
    scan_write_kernel<<<NBLK, 1024, 0, stream>>>(counts, blockOffs, row_ptr);
    fill_kernel<<<eg, 256, 0, stream>>>(edge_row, edge_col, edge_val, row_ptr, rank, sorted, E);

    deg_hist_kernel<<<(N + 1023) / 1024, 1024, 0, stream>>>(counts, dhist);
    deg_scan_kernel<<<1, 64, 0, stream>>>(dhist, dcur);
    perm_kernel<<<(N + 1023) / 1024, 1024, 0, stream>>>(counts, dcur, perm);

    prep_embed_kernel<<<(N * 16 + 255) / 256, 256, 0, stream>>>(
        (const float4*)embed, (float4*)out, embed_h);

    layer_kernel<64, 64><<<(N + 15) / 16, 256, 0, stream>>>(embed_h, sorted, row_ptr, perm,
        w1_0, b1_0, w2_0, b2_0, ego1_h, out + 64, N);
    layer_kernel<64, 32><<<(N + 15) / 16, 256, 0, stream>>>((const half4_t*)ego1_h, sorted, row_ptr, perm,
        w1_1, b1_1, w2_1, b2_1, ego2_h, out + 128, N);
    layer_kernel<32, 16><<<(N + 31) / 32, 256, 0, stream>>>((const half4_t*)ego2_h, sorted, row_ptr, perm,
        w1_2, b1_2, w2_2, b2_2, nullptr, out + 160, N);
}

// Round 5
// 254.793 us; speedup vs baseline: 4.5811x; 4.5811x over previous
//
#include <hip/hip_runtime.h>

// KGAT 3-layer forward. Inputs (all f32/int32, setup_inputs order):
// 0 embed[N,64], 1 w1_0[64,64], 2 b1_0, 3 w2_0, 4 b2_0,
// 5 w1_1[32,64], 6 b1_1, 7 w2_1, 8 b2_1, 9 w1_2[16,32], 10 b1_2, 11 w2_2, 12 b2_2,
// 13 edge_val[E], 14 edge_row[E], 15 edge_col[E]
// Output f32 [N,176] = [embed | l2n(ego1) | l2n(ego2) | l2n(ego3)]

#define NODES 100000
#define OUT_STRIDE 176

typedef _Float16 half2_t __attribute__((ext_vector_type(2)));
typedef _Float16 half4_t __attribute__((ext_vector_type(4)));

static constexpr int SCAN_TILE = 1024;
static constexpr int NV = NODES + 1;
static constexpr int NBLK = (NV + SCAN_TILE - 1) / SCAN_TILE;  // 98

// ---------------- CSR build ----------------

__global__ void hist_kernel(const int* __restrict__ rows, int* __restrict__ counts,
                            int* __restrict__ rank, int e) {
    int i = blockIdx.x * blockDim.x + threadIdx.x;
    if (i < e) rank[i] = atomicAdd(&counts[rows[i]], 1);
}

__global__ __launch_bounds__(1024) void scan_reduce_kernel(const int* __restrict__ counts,
                                                           int* __restrict__ blockSums) {
    int i = blockIdx.x * SCAN_TILE + threadIdx.x;
    int v = (i < NODES) ? counts[i] : 0;
    #pragma unroll
    for (int off = 32; off; off >>= 1) v += __shfl_xor(v, off);
    __shared__ int ws[16];
    int lane = threadIdx.x & 63, wid = threadIdx.x >> 6;
    if (lane == 0) ws[wid] = v;
    __syncthreads();
    if (threadIdx.x == 0) {
        int t = 0;
        for (int k = 0; k < 16; ++k) t += ws[k];
        blockSums[blockIdx.x] = t;
    }
}

__global__ void scan_offsets_kernel(const int* __restrict__ blockSums, int* __restrict__ blockOffs) {
    __shared__ int s[NBLK];
    if (threadIdx.x < NBLK) s[threadIdx.x] = blockSums[threadIdx.x];
    __syncthreads();
    if (threadIdx.x == 0) {
        int run = 0;
        for (int b = 0; b < NBLK; ++b) { int t = s[b]; s[b] = run; run += t; }
    }
    __syncthreads();
    if (threadIdx.x < NBLK) blockOffs[threadIdx.x] = s[threadIdx.x];
}

__global__ __launch_bounds__(1024) void scan_write_kernel(const int* __restrict__ counts,
                                                          const int* __restrict__ blockOffs,
                                                          int* __restrict__ row_ptr) {
    int i = blockIdx.x * SCAN_TILE + threadIdx.x;
    int lane = threadIdx.x & 63, wid = threadIdx.x >> 6;
    int v = (i < NODES) ? counts[i] : 0;
    int incl = v;
    #pragma unroll
    for (int off = 1; off < 64; off <<= 1) {
        int t = __shfl_up(incl, off);
        if (lane >= off) incl += t;
    }
    __shared__ int wsum[16];
    if (lane == 63) wsum[wid] = incl;
    __syncthreads();
    if (wid == 0) {
        int wv = (lane < 16) ? wsum[lane] : 0;
        int wincl = wv;
        #pragma unroll
        for (int off = 1; off < 16; off <<= 1) {
            int t = __shfl_up(wincl, off);
            if (lane >= off) wincl += t;
        }
        if (lane < 16) wsum[lane] = wincl - wv;  // exclusive wave offsets
    }
    __syncthreads();
    int excl = incl - v + wsum[wid] + blockOffs[blockIdx.x];
    if (i < NV) row_ptr[i] = excl;
}

// pack edge: col (17 bits) | round(val*32767) << 17
__global__ void fill_kernel(const int* __restrict__ rows, const int* __restrict__ cols,
                            const float* __restrict__ vals, const int* __restrict__ row_ptr,
                            const int* __restrict__ rank, unsigned* __restrict__ se, int e) {
    int i = blockIdx.x * blockDim.x + threadIdx.x;
    if (i < e) {
        unsigned v15 = __float2uint_rn(vals[i] * 32767.f);
        se[row_ptr[rows[i]] + rank[i]] = (unsigned)cols[i] | (v15 << 17);
    }
}

// ------- cols 0..63 = raw embed (f32) + build fp16 copy of embed -------

__global__ void prep_embed_kernel(const float4* __restrict__ x4, float4* __restrict__ out4,
                                  half4_t* __restrict__ xh) {
    int i = blockIdx.x * blockDim.x + threadIdx.x;
    if (i < NODES * 16) {
        int r = i >> 4, c = i & 15;
        float4 v = x4[i];
        out4[r * (OUT_STRIDE / 4) + c] = v;
        xh[i] = half4_t{(_Float16)v.x, (_Float16)v.y, (_Float16)v.z, (_Float16)v.w};
    }
}

// ---------------- fused layer: spmm + aggregate + l2norm ----------------
// Round-3 structure (sequential rows, grid-stride 2048 blocks). x fp16
// [n,DIN]. LPR=DIN/4 lanes/row, RPW=64/LPR rows/wave. Edge loop: packed
// u32 edges, main loop unrolled x8 (8 gathers in flight/group) + scalar
// tail. Weights/sum/bi fp16 in LDS ([d2][o] layout, conflict-free).

template <int DIN, int DOUT>
__global__ __launch_bounds__(256, 6) void layer_kernel(
    const half4_t* __restrict__ xh, const unsigned* __restrict__ edges,
    const int* __restrict__ row_ptr,
    const float* __restrict__ w1, const float* __restrict__ b1,
    const float* __restrict__ w2, const float* __restrict__ b2,
    _Float16* __restrict__ ego_out,  // [n, DOUT] fp16 (null for last layer)
    float* __restrict__ outp,        // d_out + column offset, row stride 176
    int n) {
    constexpr int LPR = DIN / 4;        // lanes per row
    constexpr int RPW = 64 / LPR;       // rows per wave
    constexpr int RPB = 4 * RPW;        // rows per block
    constexpr int OPL = DOUT / LPR;     // outputs per lane
    constexpr int PADH = 4;             // halves; groups on distinct banks, 8B align
    constexpr int SROW = DIN + PADH;

    __shared__ half2_t w1h[(DIN / 2) * DOUT], w2h[(DIN / 2) * DOUT];  // [d2][o]
    __shared__ _Float16 sum_h[4][RPW][SROW], bi_h[4][RPW][SROW];

    // destination-contiguous staging: conflict-free LDS writes
    for (int idx = threadIdx.x; idx < (DIN / 2) * DOUT; idx += 256) {
        int d2 = idx / DOUT, o = idx % DOUT;      // w is [DOUT][DIN] row-major
        w1h[idx] = half2_t{(_Float16)w1[o * DIN + 2 * d2], (_Float16)w1[o * DIN + 2 * d2 + 1]};
        w2h[idx] = half2_t{(_Float16)w2[o * DIN + 2 * d2], (_Float16)w2[o * DIN + 2 * d2 + 1]};
    }
    __syncthreads();

    int wid = threadIdx.x >> 6, lane = threadIdx.x & 63;
    int g = lane / LPR;     // row-group within wave
    int li = lane % LPR;    // half4 chunk within row
    int o0 = li * OPL;

    float bb1[OPL], bb2[OPL];
    #pragma unroll
    for (int k = 0; k < OPL; ++k) { bb1[k] = b1[o0 + k]; bb2[k] = b2[o0 + k]; }

    for (int base = blockIdx.x * RPB; base < n; base += gridDim.x * RPB) {
        int r = base + wid * RPW + g;
        bool valid = r < n;
        int rr = valid ? r : 0;
        int s = valid ? row_ptr[rr] : 0;
        int e = valid ? row_ptr[rr + 1] : 0;

        half4_t egoh = xh[(size_t)rr * LPR + li];  // issue early
        float sx = 0.f, sy = 0.f, sz = 0.f, sw_ = 0.f;

        int j = s;
        for (; j + 7 < e; j += 8) {
            unsigned pk[8];
            half4_t xv[8];
            #pragma unroll
            for (int k = 0; k < 8; ++k) pk[k] = edges[j + k];
            #pragma unroll
            for (int k = 0; k < 8; ++k)
                xv[k] = xh[(size_t)(pk[k] & 0x1FFFFu) * LPR + li];
            #pragma unroll
            for (int k = 0; k < 8; ++k) {
                float vf = (float)(pk[k] >> 17);
                sx += vf * (float)xv[k].x;
                sy += vf * (float)xv[k].y;
                sz += vf * (float)xv[k].z;
                sw_ += vf * (float)xv[k].w;
            }
        }
        for (; j < e; ++j) {
            unsigned p = edges[j];
            float vf = (float)(p >> 17);
            half4_t xv = xh[(size_t)(p & 0x1FFFFu) * LPR + li];
            sx += vf * (float)xv.x; sy += vf * (float)xv.y;
            sz += vf * (float)xv.z; sw_ += vf * (float)xv.w;
        }
        constexpr float SCL = 1.f / 32767.f;
        float4 side = make_float4(sx * SCL, sy * SCL, sz * SCL, sw_ * SCL);

        float ex = (float)egoh.x, ey = (float)egoh.y, ez = (float)egoh.z, ew = (float)egoh.w;
        half4_t sm4 = half4_t{(_Float16)(ex + side.x), (_Float16)(ey + side.y),
                              (_Float16)(ez + side.z), (_Float16)(ew + side.w)};
        half4_t bi4 = half4_t{(_Float16)(ex * side.x), (_Float16)(ey * side.y),
                              (_Float16)(ez * side.z), (_Float16)(ew * side.w)};
        *(half4_t*)&sum_h[wid][g][li * 4] = sm4;   // wave-private, no barrier
        *(half4_t*)&bi_h[wid][g][li * 4] = bi4;

        float a1[OPL], a2[OPL];
        #pragma unroll
        for (int k = 0; k < OPL; ++k) { a1[k] = bb1[k]; a2[k] = bb2[k]; }
        #pragma unroll 8
        for (int d2 = 0; d2 < DIN / 2; ++d2) {
            half2_t sv = *(const half2_t*)&sum_h[wid][g][2 * d2];
            half2_t tv = *(const half2_t*)&bi_h[wid][g][2 * d2];
            #pragma unroll
            for (int k = 0; k < OPL; ++k) {
                half2_t wa = w1h[d2 * DOUT + o0 + k];
                half2_t wb = w2h[d2 * DOUT + o0 + k];
#if __has_builtin(__builtin_amdgcn_fdot2)
                a1[k] = __builtin_amdgcn_fdot2(sv, wa, a1[k], false);
                a2[k] = __builtin_amdgcn_fdot2(tv, wb, a2[k], false);
#else
                a1[k] = fmaf((float)sv.x, (float)wa.x, fmaf((float)sv.y, (float)wa.y, a1[k]));
                a2[k] = fmaf((float)tv.x, (float)wb.x, fmaf((float)tv.y, (float)wb.y, a2[k]));
#endif
            }
        }
        float ov[OPL];
        float sq = 0.f;
        #pragma unroll
        for (int k = 0; k < OPL; ++k) {
            float u1 = a1[k] > 0.f ? a1[k] : 0.01f * a1[k];
            float u2 = a2[k] > 0.f ? a2[k] : 0.01f * a2[k];
            ov[k] = u1 + u2;
            sq += ov[k] * ov[k];
        }
        #pragma unroll
        for (int off = 1; off < LPR; off <<= 1) sq += __shfl_xor(sq, off);
        float inv = 1.f / fmaxf(sqrtf(sq), 1e-12f);

        if (valid) {
            if (ego_out) {
                #pragma unroll
                for (int k = 0; k < OPL; ++k)
                    ego_out[(size_t)r * DOUT + o0 + k] = (_Float16)ov[k];
            }
            #pragma unroll
            for (int k = 0; k < OPL; ++k)
                outp[(size_t)r * OUT_STRIDE + o0 + k] = ov[k] * inv;
        }
    }
}

// ---------------- launch ----------------

static size_t align_up(size_t x) { return (x + 255) & ~(size_t)255; }

extern "C" void kernel_launch(void* const* d_in, const int* in_sizes, int n_in,
                              void* d_out, int out_size, void* d_ws, size_t ws_size,
                              hipStream_t stream) {
    const float* embed = (const float*)d_in[0];
    const float* w1_0 = (const float*)d_in[1];  const float* b1_0 = (const float*)d_in[2];
    const float* w2_0 = (const float*)d_in[3];  const float* b2_0 = (const float*)d_in[4];
    const float* w1_1 = (const float*)d_in[5];  const float* b1_1 = (const float*)d_in[6];
    const float* w2_1 = (const float*)d_in[7];  const float* b2_1 = (const float*)d_in[8];
    const float* w1_2 = (const float*)d_in[9];  const float* b1_2 = (const float*)d_in[10];
    const float* w2_2 = (const float*)d_in[11]; const float* b2_2 = (const float*)d_in[12];
    const float* edge_val = (const float*)d_in[13];
    const int*   edge_row = (const int*)d_in[14];
    const int*   edge_col = (const int*)d_in[15];
    const int E = in_sizes[14];
    const int N = in_sizes[0] / 64;
    float* out = (float*)d_out;

    // workspace carve-up (~38 MB)
    char* ws = (char*)d_ws;
    size_t off = 0;
    int* counts    = (int*)(ws + off); off = align_up(off + (size_t)N * 4);
    int* row_ptr   = (int*)(ws + off); off = align_up(off + (size_t)(N + 1) * 4);
    int* rank      = (int*)(ws + off); off = align_up(off + (size_t)E * 4);
    int* blockSums = (int*)(ws + off); off = align_up(off + (size_t)NBLK * 4);
    int* blockOffs = (int*)(ws + off); off = align_up(off + (size_t)NBLK * 4);
    unsigned* sorted = (unsigned*)(ws + off); off = align_up(off + (size_t)E * 4);
    half4_t* embed_h = (half4_t*)(ws + off); off = align_up(off + (size_t)N * 64 * 2);
    _Float16* ego1_h = (_Float16*)(ws + off); off = align_up(off + (size_t)N * 64 * 2);
    _Float16* ego2_h = (_Float16*)(ws + off); off = align_up(off + (size_t)N * 32 * 2);
    (void)ws_size; (void)n_in; (void)out_size;

    hipMemsetAsync(counts, 0, (size_t)N * 4, stream);

    int eg = (E + 255) / 256;
    hist_kernel<<<eg, 256, 0, stream>>>(edge_row, counts, rank, E);
    scan_reduce_kernel<<<NBLK, 1024, 0, stream>>>(counts, blockSums);
    scan_offsets_kernel<<<1, 128, 0, stream>>>(blockSums, blockOffs);
    scan_write_kernel<<<NBLK, 1024, 0, stream>>>(counts, blockOffs, row_ptr);
    fill_kernel<<<eg, 256, 0, stream>>>(edge_row, edge_col, edge_val, row_ptr, rank, sorted, E);

    prep_embed_kernel<<<(N * 16 + 255) / 256, 256, 0, stream>>>(
        (const float4*)embed, (float4*)out, embed_h);

    layer_kernel<64, 64><<<2048, 256, 0, stream>>>(embed_h, sorted, row_ptr,
        w1_0, b1_0, w2_0, b2_0, ego1_h, out + 64, N);
    layer_kernel<64, 32><<<2048, 256, 0, stream>>>((const half4_t*)ego1_h, sorted, row_ptr,
        w1_1, b1_1, w2_1, b2_1, ego2_h, out + 128, N);
    layer_kernel<32, 16><<<2048, 256, 0, stream>>>((const half4_t*)ego2_h, sorted, row_ptr,
        w1_2, b1_2, w2_2, b2_2, nullptr, out + 160, N);
}

// Round 6
// 193.082 us; speedup vs baseline: 6.0452x; 1.3196x over previous
//
#include <hip/hip_runtime.h>

// KGAT 3-layer forward. Inputs (all f32/int32, setup_inputs order):
// 0 embed[N,64], 1 w1_0[64,64], 2 b1_0, 3 w2_0, 4 b2_0,
// 5 w1_1[32,64], 6 b1_1, 7 w2_1, 8 b2_1, 9 w1_2[16,32], 10 b1_2, 11 w2_2, 12 b2_2,
// 13 edge_val[E], 14 edge_row[E], 15 edge_col[E]
// Output f32 [N,176] = [embed | l2n(ego1) | l2n(ego2) | l2n(ego3)]

#define NODES 100000
#define OUT_STRIDE 176

typedef _Float16 f16x8 __attribute__((ext_vector_type(8)));
typedef float f32x4 __attribute__((ext_vector_type(4)));
typedef _Float16 half4_t __attribute__((ext_vector_type(4)));

static constexpr int SCAN_TILE = 1024;
static constexpr int NV = NODES + 1;
static constexpr int NBLK = (NV + SCAN_TILE - 1) / SCAN_TILE;  // 98

// ---------------- CSR build (unchanged, proven) ----------------

__global__ void hist_kernel(const int* __restrict__ rows, int* __restrict__ counts,
                            int* __restrict__ rank, int e) {
    int i = blockIdx.x * blockDim.x + threadIdx.x;
    if (i < e) rank[i] = atomicAdd(&counts[rows[i]], 1);
}

__global__ __launch_bounds__(1024) void scan_reduce_kernel(const int* __restrict__ counts,
                                                           int* __restrict__ blockSums) {
    int i = blockIdx.x * SCAN_TILE + threadIdx.x;
    int v = (i < NODES) ? counts[i] : 0;
    #pragma unroll
    for (int off = 32; off; off >>= 1) v += __shfl_xor(v, off);
    __shared__ int ws[16];
    int lane = threadIdx.x & 63, wid = threadIdx.x >> 6;
    if (lane == 0) ws[wid] = v;
    __syncthreads();
    if (threadIdx.x == 0) {
        int t = 0;
        for (int k = 0; k < 16; ++k) t += ws[k];
        blockSums[blockIdx.x] = t;
    }
}

__global__ void scan_offsets_kernel(const int* __restrict__ blockSums, int* __restrict__ blockOffs) {
    __shared__ int s[NBLK];
    if (threadIdx.x < NBLK) s[threadIdx.x] = blockSums[threadIdx.x];
    __syncthreads();
    if (threadIdx.x == 0) {
        int run = 0;
        for (int b = 0; b < NBLK; ++b) { int t = s[b]; s[b] = run; run += t; }
    }
    __syncthreads();
    if (threadIdx.x < NBLK) blockOffs[threadIdx.x] = s[threadIdx.x];
}

__global__ __launch_bounds__(1024) void scan_write_kernel(const int* __restrict__ counts,
                                                          const int* __restrict__ blockOffs,
                                                          int* __restrict__ row_ptr) {
    int i = blockIdx.x * SCAN_TILE + threadIdx.x;
    int lane = threadIdx.x & 63, wid = threadIdx.x >> 6;
    int v = (i < NODES) ? counts[i] : 0;
    int incl = v;
    #pragma unroll
    for (int off = 1; off < 64; off <<= 1) {
        int t = __shfl_up(incl, off);
        if (lane >= off) incl += t;
    }
    __shared__ int wsum[16];
    if (lane == 63) wsum[wid] = incl;
    __syncthreads();
    if (wid == 0) {
        int wv = (lane < 16) ? wsum[lane] : 0;
        int wincl = wv;
        #pragma unroll
        for (int off = 1; off < 16; off <<= 1) {
            int t = __shfl_up(wincl, off);
            if (lane >= off) wincl += t;
        }
        if (lane < 16) wsum[lane] = wincl - wv;  // exclusive wave offsets
    }
    __syncthreads();
    int excl = incl - v + wsum[wid] + blockOffs[blockIdx.x];
    if (i < NV) row_ptr[i] = excl;
}

// pack edge: col (17 bits) | round(val*32767) << 17
__global__ void fill_kernel(const int* __restrict__ rows, const int* __restrict__ cols,
                            const float* __restrict__ vals, const int* __restrict__ row_ptr,
                            const int* __restrict__ rank, unsigned* __restrict__ se, int e) {
    int i = blockIdx.x * blockDim.x + threadIdx.x;
    if (i < e) {
        unsigned v15 = __float2uint_rn(vals[i] * 32767.f);
        se[row_ptr[rows[i]] + rank[i]] = (unsigned)cols[i] | (v15 << 17);
    }
}

// ------- cols 0..63 = raw embed (f32) + build fp16 copy of embed -------

__global__ void prep_embed_kernel(const float4* __restrict__ x4, float4* __restrict__ out4,
                                  half4_t* __restrict__ xh) {
    int i = blockIdx.x * blockDim.x + threadIdx.x;
    if (i < NODES * 16) {
        int r = i >> 4, c = i & 15;
        float4 v = x4[i];
        out4[r * (OUT_STRIDE / 4) + c] = v;
        xh[i] = half4_t{(_Float16)v.x, (_Float16)v.y, (_Float16)v.z, (_Float16)v.w};
    }
}

// ---------------- fused layer: spmm + MFMA aggregate + l2norm ----------------
// One wave = 16 rows. Gather: 4 lanes/row, DPL=DIN/4 dims/lane, fp16 table,
// packed u32 edges, unroll-4. Sum/bi staged as fp16 [16][DIN+8] wave-private
// tile. Aggregation: mfma_f32_16x16x32_f16 with weight B-fragments
// pre-formatted in LDS once per block; C initialized to bias; leaky+add in
// register; l2norm via 16-lane shfl; coalesced stores.
//
// MFMA 16x16x32 f16 layouts (CDNA): A: lane l holds row (l&15), k=(l>>4)*8+j.
// B: lane l holds col (l&15), k=(l>>4)*8+j. D: col=(l&15), row=(l>>4)*4+reg
// [verified m89]. Any common k-permutation cancels between A and B.

template <int DIN, int DOUT>
__global__ __launch_bounds__(256, 4) void layer_kernel(
    const _Float16* __restrict__ xh, const unsigned* __restrict__ edges,
    const int* __restrict__ row_ptr,
    const float* __restrict__ w1, const float* __restrict__ b1,
    const float* __restrict__ w2, const float* __restrict__ b2,
    _Float16* __restrict__ ego_out,  // [n, DOUT] fp16 (null for last layer)
    float* __restrict__ outp,        // d_out + column offset, row stride 176
    int n) {
    constexpr int KT = DIN / 32;        // MFMA K-tiles
    constexpr int NT = DOUT / 16;       // MFMA N-tiles
    constexpr int NFRAG = 2 * KT * NT;  // weight fragments (w1 + w2)
    constexpr int DPL = DIN / 4;        // dims per lane in gather phase
    constexpr int C8 = DPL / 8;         // f16x8 chunks per lane
    constexpr int SROWH = DIN + 8;      // halves per tile row (pad: 2-way banks)

    __shared__ f16x8 wfrag[NFRAG * 64];
    __shared__ _Float16 tiles[4][2][16 * SROWH];  // [wave][sum|bi][row*SROWH]

    // ---- stage weight B-fragments once per block ----
    for (int slot = threadIdx.x; slot < NFRAG * 64; slot += 256) {
        int l = slot & 63, fid = slot >> 6;
        int mat = fid / (KT * NT);
        int kt = (fid / NT) % KT;
        int nt = fid % NT;
        const float* w = mat ? w2 : w1;
        int o = nt * 16 + (l & 15);
        int kb = kt * 32 + (l >> 4) * 8;
        const float* src = w + o * DIN + kb;
        f16x8 f;
        #pragma unroll
        for (int jj = 0; jj < 8; ++jj) f[jj] = (_Float16)src[jj];
        wfrag[slot] = f;
    }
    __syncthreads();

    int wid = threadIdx.x >> 6, lane = threadIdx.x & 63;
    int g = lane >> 2, li = lane & 3;   // gather: row-in-tile, dim-chunk
    int q = lane >> 4, cl = lane & 15;  // mfma: quarter, col-in-tile

    float bias1[NT], bias2[NT];
    #pragma unroll
    for (int nt = 0; nt < NT; ++nt) {
        bias1[nt] = b1[nt * 16 + cl];
        bias2[nt] = b2[nt * 16 + cl];
    }

    int r0 = blockIdx.x * 64 + wid * 16;  // wave's tile base (one-shot grid)

    // ---- gather phase ----
    int r = r0 + g;
    bool valid = r < n;
    int rr = valid ? r : 0;
    int s = valid ? row_ptr[rr] : 0;
    int e = valid ? row_ptr[rr + 1] : 0;

    const _Float16* xrow = xh + (size_t)rr * DIN + li * DPL;
    f16x8 egoh[C8];
    #pragma unroll
    for (int c = 0; c < C8; ++c) egoh[c] = *(const f16x8*)(xrow + c * 8);

    float sd[DPL];
    #pragma unroll
    for (int d = 0; d < DPL; ++d) sd[d] = 0.f;

    const _Float16* xbase = xh + li * DPL;
    int j = s;
    for (; j + 3 < e; j += 4) {
        unsigned pk[4];
        #pragma unroll
        for (int k = 0; k < 4; ++k) pk[k] = edges[j + k];
        f16x8 xv[4][C8];
        #pragma unroll
        for (int k = 0; k < 4; ++k) {
            const _Float16* p = xbase + (size_t)(pk[k] & 0x1FFFFu) * DIN;
            #pragma unroll
            for (int c = 0; c < C8; ++c) xv[k][c] = *(const f16x8*)(p + c * 8);
        }
        #pragma unroll
        for (int k = 0; k < 4; ++k) {
            float vf = (float)(pk[k] >> 17);
            #pragma unroll
            for (int c = 0; c < C8; ++c)
                #pragma unroll
                for (int d = 0; d < 8; ++d)
                    sd[c * 8 + d] += vf * (float)xv[k][c][d];
        }
    }
    for (; j < e; ++j) {
        unsigned p = edges[j];
        float vf = (float)(p >> 17);
        const _Float16* xp = xbase + (size_t)(p & 0x1FFFFu) * DIN;
        #pragma unroll
        for (int c = 0; c < C8; ++c) {
            f16x8 xv = *(const f16x8*)(xp + c * 8);
            #pragma unroll
            for (int d = 0; d < 8; ++d) sd[c * 8 + d] += vf * (float)xv[d];
        }
    }

    // sum/bi -> fp16 tile (wave-private; same-wave RAW ordered by lgkmcnt)
    _Float16* srow = &tiles[wid][0][g * SROWH + li * DPL];
    _Float16* brow = &tiles[wid][1][g * SROWH + li * DPL];
    constexpr float SCL = 1.f / 32767.f;
    #pragma unroll
    for (int c = 0; c < C8; ++c) {
        f16x8 sm, bi;
        #pragma unroll
        for (int d = 0; d < 8; ++d) {
            float egof = (float)egoh[c][d];
            float sv = sd[c * 8 + d] * SCL;
            sm[d] = (_Float16)(egof + sv);
            bi[d] = (_Float16)(egof * sv);
        }
        *(f16x8*)(srow + c * 8) = sm;
        *(f16x8*)(brow + c * 8) = bi;
    }

    // ---- MFMA phase ----
    f16x8 sumA[KT], biA[KT];
    #pragma unroll
    for (int kt = 0; kt < KT; ++kt) {
        sumA[kt] = *(const f16x8*)&tiles[wid][0][cl * SROWH + kt * 32 + q * 8];
        biA[kt]  = *(const f16x8*)&tiles[wid][1][cl * SROWH + kt * 32 + q * 8];
    }

    float ov[NT][4];
    #pragma unroll
    for (int nt = 0; nt < NT; ++nt) {
        f32x4 c1 = {bias1[nt], bias1[nt], bias1[nt], bias1[nt]};
        f32x4 c2 = {bias2[nt], bias2[nt], bias2[nt], bias2[nt]};
        #pragma unroll
        for (int kt = 0; kt < KT; ++kt) {
            f16x8 wa = wfrag[((0 * KT + kt) * NT + nt) * 64 + lane];
            f16x8 wb = wfrag[((1 * KT + kt) * NT + nt) * 64 + lane];
            c1 = __builtin_amdgcn_mfma_f32_16x16x32_f16(sumA[kt], wa, c1, 0, 0, 0);
            c2 = __builtin_amdgcn_mfma_f32_16x16x32_f16(biA[kt], wb, c2, 0, 0, 0);
        }
        #pragma unroll
        for (int t = 0; t < 4; ++t) {
            float u1 = c1[t] > 0.f ? c1[t] : 0.01f * c1[t];
            float u2 = c2[t] > 0.f ? c2[t] : 0.01f * c2[t];
            ov[nt][t] = u1 + u2;
        }
    }

    // ---- l2norm + stores: row = r0 + 4q + t, col = nt*16 + cl ----
    #pragma unroll
    for (int t = 0; t < 4; ++t) {
        float sq = 0.f;
        #pragma unroll
        for (int nt = 0; nt < NT; ++nt) sq += ov[nt][t] * ov[nt][t];
        #pragma unroll
        for (int off = 1; off < 16; off <<= 1) sq += __shfl_xor(sq, off);
        float inv = 1.f / fmaxf(sqrtf(sq), 1e-12f);
        int rw = r0 + 4 * q + t;
        if (rw < n) {
            #pragma unroll
            for (int nt = 0; nt < NT; ++nt) {
                float o = ov[nt][t];
                if (ego_out) ego_out[(size_t)rw * DOUT + nt * 16 + cl] = (_Float16)o;
                outp[(size_t)rw * OUT_STRIDE + nt * 16 + cl] = o * inv;
            }
        }
    }
}

// ---------------- launch ----------------

static size_t align_up(size_t x) { return (x + 255) & ~(size_t)255; }

extern "C" void kernel_launch(void* const* d_in, const int* in_sizes, int n_in,
                              void* d_out, int out_size, void* d_ws, size_t ws_size,
                              hipStream_t stream) {
    const float* embed = (const float*)d_in[0];
    const float* w1_0 = (const float*)d_in[1];  const float* b1_0 = (const float*)d_in[2];
    const float* w2_0 = (const float*)d_in[3];  const float* b2_0 = (const float*)d_in[4];
    const float* w1_1 = (const float*)d_in[5];  const float* b1_1 = (const float*)d_in[6];
    const float* w2_1 = (const float*)d_in[7];  const float* b2_1 = (const float*)d_in[8];
    const float* w1_2 = (const float*)d_in[9];  const float* b1_2 = (const float*)d_in[10];
    const float* w2_2 = (const float*)d_in[11]; const float* b2_2 = (const float*)d_in[12];
    const float* edge_val = (const float*)d_in[13];
    const int*   edge_row = (const int*)d_in[14];
    const int*   edge_col = (const int*)d_in[15];
    const int E = in_sizes[14];
    const int N = in_sizes[0] / 64;
    float* out = (float*)d_out;

    // workspace carve-up (~38 MB)
    char* ws = (char*)d_ws;
    size_t off = 0;
    int* counts    = (int*)(ws + off); off = align_up(off + (size_t)N * 4);
    int* row_ptr   = (int*)(ws + off); off = align_up(off + (size_t)(N + 1) * 4);
    int* rank      = (int*)(ws + off); off = align_up(off + (size_t)E * 4);
    int* blockSums = (int*)(ws + off); off = align_up(off + (size_t)NBLK * 4);
    int* blockOffs = (int*)(ws + off); off = align_up(off + (size_t)NBLK * 4);
    unsigned* sorted = (unsigned*)(ws + off); off = align_up(off + (size_t)E * 4);
    _Float16* embed_h = (_Float16*)(ws + off); off = align_up(off + (size_t)N * 64 * 2);
    _Float16* ego1_h  = (_Float16*)(ws + off); off = align_up(off + (size_t)N * 64 * 2);
    _Float16* ego2_h  = (_Float16*)(ws + off); off = align_up(off + (size_t)N * 32 * 2);
    (void)ws_size; (void)n_in; (void)out_size;

    hipMemsetAsync(counts, 0, (size_t)N * 4, stream);

    int eg = (E + 255) / 256;
    hist_kernel<<<eg, 256, 0, stream>>>(edge_row, counts, rank, E);
    scan_reduce_kernel<<<NBLK, 1024, 0, stream>>>(counts, blockSums);
    scan_offsets_kernel<<<1, 128, 0, stream>>>(blockSums, blockOffs);
    scan_write_kernel<<<NBLK, 1024, 0, stream>>>(counts, blockOffs, row_ptr);
    fill_kernel<<<eg, 256, 0, stream>>>(edge_row, edge_col, edge_val, row_ptr, rank, sorted, E);

    prep_embed_kernel<<<(N * 16 + 255) / 256, 256, 0, stream>>>(
        (const float4*)embed, (float4*)out, (half4_t*)embed_h);

    int lb = (N + 63) / 64;  // one 16-row tile per wave, one-shot
    layer_kernel<64, 64><<<lb, 256, 0, stream>>>(embed_h, sorted, row_ptr,
        w1_0, b1_0, w2_0, b2_0, ego1_h, out + 64, N);
    layer_kernel<64, 32><<<lb, 256, 0, stream>>>(ego1_h, sorted, row_ptr,
        w1_1, b1_1, w2_1, b2_1, ego2_h, out + 128, N);
    layer_kernel<32, 16><<<lb, 256, 0, stream>>>(ego2_h, sorted, row_ptr,
        w1_2, b1_2, w2_2, b2_2, nullptr, out + 160, N);
}